// Round 6
// baseline (177.081 us; speedup 1.0000x reference)
//
#include <hip/hip_runtime.h>

#define IMG 224
#define HW (IMG * IMG)
#define TILE 32
#define PAD 4
#define REG (TILE + 2 * PAD)       // 40: staged rows/cols per tile
#define RST (REG + 1)              // 41: LDS row stride (odd -> bank spread)
#define TSZ (REG * RST)            // 1640 bf16 elements per staged tile

static inline __device__ float bf2f(unsigned short u) {
    union { unsigned int i; float f; } x;
    x.i = ((unsigned int)u) << 16;
    return x.f;
}
static inline __device__ unsigned short f2bf(float f) {
    union { float f; unsigned int i; } x;
    x.f = f;
    unsigned int b = x.i;
    b += 0x7fffu + ((b >> 16) & 1u);   // RNE
    return (unsigned short)(b >> 16);
}

__global__ __launch_bounds__(256, 8) void vm_kernel(
    const float* __restrict__ im1, const float* __restrict__ im2,
    const float* __restrict__ C, const float* __restrict__ M1,
    const float* __restrict__ M2, float* __restrict__ out)
{
    // 6 bf16 staged tiles (im1 ch0..2, im2 ch0..2), flat-clamp baked in.
    // 19,680 B -> 8 blocks/CU (32 waves, full wave-slot occupancy).
    __shared__ unsigned short sT[6 * TSZ];

    const int n    = blockIdx.y;
    const int tile = blockIdx.x;           // 0..48
    const int x0   = (tile / 7) * TILE;    // gather col coord (p / 224)
    const int y0   = (tile % 7) * TILE;    // gather row coord (p % 224)
    const int t    = threadIdx.x;
    const int xlo  = x0 - PAD;
    const int ylo  = y0 - PAD;

    const float* i1n = im1 + (size_t)n * 3 * HW;
    const float* i2n = im2 + (size_t)n * 3 * HW;
    const float* Cn  = C  + (size_t)n * 2 * HW;
    const float* M1n = M1 + (size_t)n * HW;
    const float* M2n = M2 + (size_t)n * HW;

    // ---- phase 1: stage all 6 channel tiles as bf16. All 42 global loads
    //      independent, issued before the single barrier.
#pragma unroll
    for (int k = 0; k < 7; ++k) {
        int e = t + 256 * k;
        if (e < REG * REG) {               // only k=6 partial (wave-uniform)
            int r  = e / REG;
            int c  = e - r * REG;
            int gi = (xlo + c) + IMG * (ylo + r);   // reference flat clamp
            gi = min(max(gi, 0), HW - 1);
            int ls = r * RST + c;
            float v0 = i1n[0 * HW + gi];
            float v1 = i1n[1 * HW + gi];
            float v2 = i1n[2 * HW + gi];
            float v3 = i2n[0 * HW + gi];
            float v4 = i2n[1 * HW + gi];
            float v5 = i2n[2 * HW + gi];
            sT[0 * TSZ + ls] = f2bf(v0);
            sT[1 * TSZ + ls] = f2bf(v1);
            sT[2 * TSZ + ls] = f2bf(v2);
            sT[3 * TSZ + ls] = f2bf(v3);
            sT[4 * TSZ + ls] = f2bf(v4);
            sT[5 * TSZ + ls] = f2bf(v5);
        }
    }

    // ---- C/M straight to registers, natural (y-fast) order -> coalesced.
    float c0[4], c1[4], m1v[4], m2v[4];
#pragma unroll
    for (int j = 0; j < 4; ++j) {
        int idx = t + 256 * j;
        int tx  = idx >> 5;
        int ty  = idx & 31;
        int p   = (x0 + tx) * IMG + (y0 + ty);
        c0[j]  = Cn[p];
        c1[j]  = Cn[HW + p];
        m1v[j] = M1n[p];
        m2v[j] = M2n[p];
    }

    __syncthreads();                       // the ONLY barrier

    // ---- phase 2: per pixel compute, bf16 LDS gathers, direct store.
    float* on = out + (size_t)n * 3 * HW;
#pragma unroll
    for (int j = 0; j < 4; ++j) {
        int idx = t + 256 * j;
        int tx  = idx >> 5;
        int ty  = idx & 31;
        int p   = (x0 + tx) * IMG + (y0 + ty);
        float xf = (float)(x0 + tx);
        float yf = (float)(y0 + ty);

        int   oA[4], oB[4];
        float wA[4], wB[4];
        int fa, fb;
        {   // +C on im1
            float px = xf + c0[j], py = yf + c1[j];
            float fx = floorf(px), cx = ceilf(px);
            float fy = floorf(py), cy = ceilf(py);
            float wfx = 1.0f - (px - fx), wcx = 1.0f - (cx - px);
            float wfy = 1.0f - (py - fy), wcy = 1.0f - (cy - py);
            wA[0] = wfx * wfy; wA[1] = wcx * wfy;
            wA[2] = wfx * wcy; wA[3] = wcx * wcy;
            int gx0 = (int)fx, gy0 = (int)fy;
            int dx = (int)cx - gx0, dy = (int)cy - gy0;
            int q0 = gx0 - xlo, r0 = gy0 - ylo;
            int o  = r0 * RST + q0;
            oA[0] = o;            oA[1] = o + dx;
            oA[2] = o + dy * RST; oA[3] = o + dx + dy * RST;
            fa = __all((q0 >= 0) & (q0 + dx <= REG - 1) &
                       (r0 >= 0) & (r0 + dy <= REG - 1));
        }
        {   // -C on im2
            float px = xf - c0[j], py = yf - c1[j];
            float fx = floorf(px), cx = ceilf(px);
            float fy = floorf(py), cy = ceilf(py);
            float wfx = 1.0f - (px - fx), wcx = 1.0f - (cx - px);
            float wfy = 1.0f - (py - fy), wcy = 1.0f - (cy - py);
            wB[0] = wfx * wfy; wB[1] = wcx * wfy;
            wB[2] = wfx * wcy; wB[3] = wcx * wcy;
            int gx0 = (int)fx, gy0 = (int)fy;
            int dx = (int)cx - gx0, dy = (int)cy - gy0;
            int q0 = gx0 - xlo, r0 = gy0 - ylo;
            int o  = r0 * RST + q0;
            oB[0] = o;            oB[1] = o + dx;
            oB[2] = o + dy * RST; oB[3] = o + dx + dy * RST;
            fb = __all((q0 >= 0) & (q0 + dx <= REG - 1) &
                       (r0 >= 0) & (r0 + dy <= REG - 1));
        }

        float res[3];
        if (fa) {
#pragma unroll
            for (int ch = 0; ch < 3; ++ch) {
                const unsigned short* T = sT + ch * TSZ;
                res[ch] = m1v[j] *
                    (wA[0] * bf2f(T[oA[0]]) + wA[1] * bf2f(T[oA[1]]) +
                     wA[2] * bf2f(T[oA[2]]) + wA[3] * bf2f(T[oA[3]]));
            }
        } else {  // rare: displacement beyond PAD -> global clamped gather
            float px = xf + c0[j], py = yf + c1[j];
            float fx = floorf(px), cx = ceilf(px);
            float fy = floorf(py), cy = ceilf(py);
            int i0 = min(max((int)fx + IMG * (int)fy, 0), HW - 1);
            int i1 = min(max((int)cx + IMG * (int)fy, 0), HW - 1);
            int i2 = min(max((int)fx + IMG * (int)cy, 0), HW - 1);
            int i3 = min(max((int)cx + IMG * (int)cy, 0), HW - 1);
#pragma unroll
            for (int ch = 0; ch < 3; ++ch) {
                const float* pa = i1n + ch * HW;
                res[ch] = m1v[j] *
                    (wA[0] * pa[i0] + wA[1] * pa[i1] +
                     wA[2] * pa[i2] + wA[3] * pa[i3]);
            }
        }
        if (fb) {
#pragma unroll
            for (int ch = 0; ch < 3; ++ch) {
                const unsigned short* T = sT + (3 + ch) * TSZ;
                res[ch] += m2v[j] *
                    (wB[0] * bf2f(T[oB[0]]) + wB[1] * bf2f(T[oB[1]]) +
                     wB[2] * bf2f(T[oB[2]]) + wB[3] * bf2f(T[oB[3]]));
            }
        } else {
            float px = xf - c0[j], py = yf - c1[j];
            float fx = floorf(px), cx = ceilf(px);
            float fy = floorf(py), cy = ceilf(py);
            int i0 = min(max((int)fx + IMG * (int)fy, 0), HW - 1);
            int i1 = min(max((int)cx + IMG * (int)fy, 0), HW - 1);
            int i2 = min(max((int)fx + IMG * (int)cy, 0), HW - 1);
            int i3 = min(max((int)cx + IMG * (int)cy, 0), HW - 1);
#pragma unroll
            for (int ch = 0; ch < 3; ++ch) {
                const float* pb = i2n + ch * HW;
                res[ch] += m2v[j] *
                    (wB[0] * pb[i0] + wB[1] * pb[i1] +
                     wB[2] * pb[i2] + wB[3] * pb[i3]);
            }
        }

        // direct coalesced store (lanes consecutive in ty -> contiguous)
#pragma unroll
        for (int ch = 0; ch < 3; ++ch)
            on[ch * HW + p] = res[ch];
    }
}

extern "C" void kernel_launch(void* const* d_in, const int* in_sizes, int n_in,
                              void* d_out, int out_size, void* d_ws, size_t ws_size,
                              hipStream_t stream) {
    const float* im1 = (const float*)d_in[0];
    const float* im2 = (const float*)d_in[1];
    const float* C   = (const float*)d_in[2];
    const float* M1  = (const float*)d_in[3];
    const float* M2  = (const float*)d_in[4];
    float* out = (float*)d_out;
    dim3 grid(49, 64);  // 7x7 tiles of 32x32, 64 batch
    vm_kernel<<<grid, 256, 0, stream>>>(im1, im2, C, M1, M2, out);
}